// Round 3
// baseline (308.378 us; speedup 1.0000x reference)
//
#include <hip/hip_runtime.h>
#include <math.h>

// ---- constants from the reference ----
#define KC        2.2281692032865347f   // 7/pi
#define H         0.05f
#define INV_H2    400.0f                // 1/h^2
#define INV_H3    8000.0f               // 1/h^3
#define EPS_REF   0.00025f              // h^2 * 0.1
#define K_OUT     0.24261080f           // 2*h*DELTA*C0
#define REST_RHO  1000.0f

#define LPN 16   // lanes per node (16 divides wave; groups never straddle waves)

__device__ __forceinline__ float wendland_dkdq(float q) {
    float omq = 1.0f - q;
    return -20.0f * q * omq * omq * omq * KC;
}

__device__ __forceinline__ float group_sum(float v) {
#pragma unroll
    for (int m = LPN / 2; m >= 1; m >>= 1) v += __shfl_xor(v, m, LPN);
    return v;
}

// rowptr[t] = first edge index e with i[e] >= t.  i is sorted ascending.
// Launch E+1 threads; every rowptr[0..N] written exactly once, no init needed.
__global__ void k_rowptr(const int* __restrict__ ei, int* __restrict__ rowptr,
                         int N, int E) {
    int e = blockIdx.x * blockDim.x + threadIdx.x;
    if (e > E) return;
    int prev = (e == 0) ? -1 : ei[e - 1];
    int cur  = (e == E) ? N  : ei[e];
    for (int t = prev + 1; t <= cur; ++t) rowptr[t] = e;
    if (e == E) rowptr[N] = E;   // cur==N already covers it; keep explicit
}

// Pass 1+2 fused: M[node] = sum_j s*dir dir^T (sym PSD), then pinv in-register.
// Writes Li4[node] = (i00, i01, i11, dens_i) and nd[node].xy = (vol_i, dens_i).
__global__ void k_M_pinv(const int* __restrict__ rowptr, const int* __restrict__ ej,
                         const float* __restrict__ qarr, const float2* __restrict__ dirs,
                         const float* __restrict__ vol, const float* __restrict__ dens,
                         float4* __restrict__ Li4, float4* __restrict__ nd, int N) {
    int tid  = blockIdx.x * blockDim.x + threadIdx.x;
    int node = tid / LPN;
    int sl   = tid % LPN;
    if (node >= N) return;
    int beg = rowptr[node], end = rowptr[node + 1];

    float m00 = 0.f, m01 = 0.f, m11 = 0.f;
    for (int e = beg + sl; e < end; e += LPN) {
        int jj = ej[e];
        float q = qarr[e];
        float2 d = dirs[e];
        float Vj = vol[jj];                       // scattered gather (L2-resident)
        float s = -2.0f * Vj * q * wendland_dkdq(q) * INV_H2;   // >= 0
        m00 += s * d.x * d.x;
        m01 += s * d.x * d.y;
        m11 += s * d.y * d.y;
    }
    m00 = group_sum(m00); m01 = group_sum(m01); m11 = group_sum(m11);

    if (sl == 0) {
        float a = m00, b = m01, c = m11;
        float half_tr   = 0.5f * (a + c);
        float half_diff = 0.5f * (a - c);
        float disc = sqrtf(half_diff * half_diff + b * b);
        float l1 = half_tr + disc, l2 = half_tr - disc;
        float smax = fmaxf(fabsf(l1), fabsf(l2));
        float cutoff = 2.3841858e-6f * smax;      // jnp pinv rcond = 10*2*eps_f32
        float i00 = 0.f, i01 = 0.f, i11 = 0.f;
        if (fabsf(l2) > cutoff) {
            float inv = 1.0f / (a * c - b * b);
            i00 =  c * inv; i01 = -b * inv; i11 = a * inv;
        } else if (fabsf(l1) > cutoff) {
            float vax = b,      vay = l1 - a;
            float vbx = l1 - c, vby = b;
            float na = vax * vax + vay * vay, nb = vbx * vbx + vby * vby;
            float vx, vy, n2;
            if (nb >= na) { vx = vbx; vy = vby; n2 = nb; }
            else          { vx = vax; vy = vay; n2 = na; }
            float inv = 1.0f / (l1 * n2);
            i00 = vx * vx * inv; i01 = vx * vy * inv; i11 = vy * vy * inv;
        }
        float di = dens[node];
        Li4[node] = make_float4(i00, i01, i11, di);
        ((float2*)nd)[2 * (size_t)node] = make_float2(vol[node], di);  // nd.xy
    }
}

// Pass 3: gradRho[node] = sum_j 2*rho_ba*Vj * grad (with change-filter fallback).
// Row-broadcast Li4; per-edge gather nd[j].xy = (vol_j, dens_j).
// Writes nd[node].zw = gradRho.
__global__ void k_gradRho(const int* __restrict__ rowptr, const int* __restrict__ ej,
                          const float* __restrict__ qarr, const float2* __restrict__ dirs,
                          const float4* __restrict__ Li4, float4* __restrict__ nd, int N) {
    int tid  = blockIdx.x * blockDim.x + threadIdx.x;
    int node = tid / LPN;
    int sl   = tid % LPN;
    if (node >= N) return;
    int beg = rowptr[node], end = rowptr[node + 1];
    float4 L = Li4[node];          // same address for all 16 lanes -> broadcast

    float sgx = 0.f, sgy = 0.f;
    for (int e = beg + sl; e < end; e += LPN) {
        int jj = ej[e];
        float q = qarr[e];
        float2 d = dirs[e];
        float2 vdj = *(const float2*)&nd[jj];     // (vol_j, dens_j), 16B-aligned
        float w = wendland_dkdq(q) * INV_H3;
        float gwx = d.x * w, gwy = d.y * w;
        float gx = L.x * gwx + L.y * gwy;
        float gy = L.y * gwx + L.z * gwy;
        float dwij_mag = fabsf(gwx) + fabsf(gwy);
        float norm_mag = fabsf(gx) + fabsf(gy);
        float change = fabsf(norm_mag - dwij_mag) / (dwij_mag + 1e-4f * H);
        if (!(change < 0.1f)) { gx = gwx; gy = gwy; }   // NaN -> fallback (jnp.where)
        float val = 2.0f * REST_RHO * (vdj.y - L.w) * vdj.x;
        sgx += val * gx;
        sgy += val * gy;
    }
    sgx = group_sum(sgx); sgy = group_sum(sgy);
    if (sl == 0)
        ((float2*)nd)[2 * (size_t)node + 1] = make_float2(sgx, sgy);  // nd.zw
}

// Pass 4: deltaSPH diffusion. Row-broadcast nd[node]; per-edge 16B gather nd[j].
__global__ void k_out(const int* __restrict__ rowptr, const int* __restrict__ ej,
                      const float* __restrict__ qarr, const float2* __restrict__ dirs,
                      const float4* __restrict__ nd, float* __restrict__ out, int N) {
    int tid  = blockIdx.x * blockDim.x + threadIdx.x;
    int node = tid / LPN;
    int sl   = tid % LPN;
    if (node >= N) return;
    int beg = rowptr[node], end = rowptr[node + 1];
    float4 ndi = nd[node];         // (vol_i, dens_i, gx_i, gy_i) broadcast

    float s = 0.f;
    for (int e = beg + sl; e < end; e += LPN) {
        int jj = ej[e];
        float q = qarr[e];
        float2 d = dirs[e];
        float4 ndj = nd[jj];                      // one 16B gather per edge
        float w = wendland_dkdq(q) * INV_H3;
        float gwx = d.x * w, gwy = d.y * w;
        float rx = -d.x * q * H, ry = -d.y * q * H;
        float rji2 = rx * rx + ry * ry + EPS_REF;
        float gradTerm = (gwx * rx + gwy * ry) / rji2;
        float densityTerm = 0.5f * ((ndi.z + ndj.z) * rx + (ndi.w + ndj.w) * ry);
        float rho_ba = REST_RHO * (ndj.y - ndi.y);
        s += (rho_ba + densityTerm) * gradTerm * ndj.x;
    }
    s = group_sum(s);
    if (sl == 0) out[node] = s * K_OUT;
}

extern "C" void kernel_launch(void* const* d_in, const int* in_sizes, int n_in,
                              void* d_out, int out_size, void* d_ws, size_t ws_size,
                              hipStream_t stream) {
    // inputs: 0 fluidPosition (unused), 1 fluidVolume[N], 2 fluidDensity[N],
    //         3 distances[E,2], 4 radialDistances[E], 5 i[E], 6 j[E]
    const float*  vol  = (const float*)d_in[1];
    const float*  dens = (const float*)d_in[2];
    const float2* dirs = (const float2*)d_in[3];
    const float*  qarr = (const float*)d_in[4];
    const int*    ei   = (const int*)d_in[5];
    const int*    ej   = (const int*)d_in[6];
    const int N = in_sizes[1];
    const int E = in_sizes[4];

    // ws layout: rowptr int[N+1] (pad to 16B) | Li4 float4[N] | nd float4[N]
    int*    rowptr = (int*)d_ws;
    size_t  ofs    = ((size_t)(N + 1) * sizeof(int) + 15) & ~(size_t)15;
    float4* Li4    = (float4*)((char*)d_ws + ofs);
    float4* nd     = Li4 + N;
    float*  out    = (float*)d_out;

    const int tb = 256;
    const int gR = (E + 1 + tb - 1) / tb;                 // rowptr build
    const int gN = ((size_t)N * LPN + tb - 1) / tb;       // node kernels

    k_rowptr <<<gR, tb, 0, stream>>>(ei, rowptr, N, E);
    k_M_pinv <<<gN, tb, 0, stream>>>(rowptr, ej, qarr, dirs, vol, dens, Li4, nd, N);
    k_gradRho<<<gN, tb, 0, stream>>>(rowptr, ej, qarr, dirs, Li4, nd, N);
    k_out    <<<gN, tb, 0, stream>>>(rowptr, ej, qarr, dirs, nd, out, N);
}

// Round 4
// 304.586 us; speedup vs baseline: 1.0125x; 1.0125x over previous
//
#include <hip/hip_runtime.h>
#include <math.h>

// ---- constants from the reference ----
#define KC        2.2281692032865347f   // 7/pi
#define H         0.05f
#define INV_H2    400.0f                // 1/h^2
#define INV_H3    8000.0f               // 1/h^3
#define EPS_REF   0.00025f              // h^2 * 0.1
#define K_OUT     0.24261080f           // 2*h*DELTA*C0
#define REST_RHO  1000.0f

#define LPN 16   // lanes per node (divides 64; groups never straddle waves)

__device__ __forceinline__ float wendland_dkdq(float q) {
    float omq = 1.0f - q;
    return -20.0f * q * omq * omq * omq * KC;
}

__device__ __forceinline__ float group_sum(float v) {
#pragma unroll
    for (int m = LPN / 2; m >= 1; m >>= 1) v += __shfl_xor(v, m, LPN);
    return v;
}

// rowptr[t] = first edge e with i[e] >= t (i sorted ascending); also pack vd=(vol,dens).
__global__ void k_prep(const int* __restrict__ ei, const float* __restrict__ vol,
                       const float* __restrict__ dens, int* __restrict__ rowptr,
                       float2* __restrict__ vd, int N, int E) {
    int e = blockIdx.x * blockDim.x + threadIdx.x;
    if (e <= E) {
        int prev = (e == 0) ? -1 : ei[e - 1];
        int cur  = (e == E) ? N  : ei[e];
        for (int t = prev + 1; t <= cur; ++t) rowptr[t] = e;
    }
    if (e < N) vd[e] = make_float2(vol[e], dens[e]);
}

// Pass 1+2 fused: gather vd[j] ONCE per edge (the only j-gather before pass 4),
// stream it out as vr[e]=(Vj,rhoj), accumulate M, pinv in-register.
// Li4[node] = (i00, i01, i11, dens_i).
template<bool WRITE_VR>
__global__ void k_M_pinv(const int* __restrict__ rowptr, const int* __restrict__ ej,
                         const float* __restrict__ qarr, const float2* __restrict__ dirs,
                         const float2* __restrict__ vd, float2* __restrict__ vr,
                         float4* __restrict__ Li4, int N) {
    int tid  = blockIdx.x * blockDim.x + threadIdx.x;
    int node = tid / LPN;
    int sl   = tid % LPN;
    if (node >= N) return;
    int beg = rowptr[node], end = rowptr[node + 1];

    float m00 = 0.f, m01 = 0.f, m11 = 0.f;
    for (int e = beg + sl; e < end; e += LPN) {
        int jj = ej[e];
        float q = qarr[e];
        float2 d = dirs[e];
        float2 vdj = vd[jj];                      // scattered: 1 line/edge
        if (WRITE_VR) vr[e] = vdj;                // coalesced stream-out
        float s = -2.0f * vdj.x * q * wendland_dkdq(q) * INV_H2;   // >= 0
        m00 += s * d.x * d.x;
        m01 += s * d.x * d.y;
        m11 += s * d.y * d.y;
    }
    m00 = group_sum(m00); m01 = group_sum(m01); m11 = group_sum(m11);

    if (sl == 0) {
        float a = m00, b = m01, c = m11;
        float half_tr   = 0.5f * (a + c);
        float half_diff = 0.5f * (a - c);
        float disc = sqrtf(half_diff * half_diff + b * b);
        float l1 = half_tr + disc, l2 = half_tr - disc;
        float smax = fmaxf(fabsf(l1), fabsf(l2));
        float cutoff = 2.3841858e-6f * smax;      // jnp pinv rcond = 10*2*eps_f32
        float i00 = 0.f, i01 = 0.f, i11 = 0.f;
        if (fabsf(l2) > cutoff) {
            float inv = 1.0f / (a * c - b * b);
            i00 =  c * inv; i01 = -b * inv; i11 = a * inv;
        } else if (fabsf(l1) > cutoff) {
            float vax = b,      vay = l1 - a;
            float vbx = l1 - c, vby = b;
            float na = vax * vax + vay * vay, nb = vbx * vbx + vby * vby;
            float vx, vy, n2;
            if (nb >= na) { vx = vbx; vy = vby; n2 = nb; }
            else          { vx = vax; vy = vay; n2 = na; }
            float inv = 1.0f / (l1 * n2);
            i00 = vx * vx * inv; i01 = vx * vy * inv; i11 = vy * vy * inv;
        }
        Li4[node] = make_float4(i00, i01, i11, vd[node].y);
    }
}

// Pass 3: ZERO gathers (fast path) — streams q, dirs, vr; row-broadcast Li4.
template<bool USE_VR>
__global__ void k_gradRho(const int* __restrict__ rowptr, const int* __restrict__ ej,
                          const float* __restrict__ qarr, const float2* __restrict__ dirs,
                          const float2* __restrict__ vr, const float2* __restrict__ vd,
                          const float4* __restrict__ Li4, float2* __restrict__ g, int N) {
    int tid  = blockIdx.x * blockDim.x + threadIdx.x;
    int node = tid / LPN;
    int sl   = tid % LPN;
    if (node >= N) return;
    int beg = rowptr[node], end = rowptr[node + 1];
    float4 L = Li4[node];          // broadcast (same address for all lanes of group)

    float sgx = 0.f, sgy = 0.f;
    for (int e = beg + sl; e < end; e += LPN) {
        float q = qarr[e];
        float2 d = dirs[e];
        float2 vdj = USE_VR ? vr[e] : vd[ej[e]];  // stream vs gather fallback
        float w = wendland_dkdq(q) * INV_H3;
        float gwx = d.x * w, gwy = d.y * w;
        float gx = L.x * gwx + L.y * gwy;
        float gy = L.y * gwx + L.z * gwy;
        float dwij_mag = fabsf(gwx) + fabsf(gwy);
        float norm_mag = fabsf(gx) + fabsf(gy);
        float change = fabsf(norm_mag - dwij_mag) / (dwij_mag + 1e-4f * H);
        if (!(change < 0.1f)) { gx = gwx; gy = gwy; }   // NaN -> fallback (jnp.where)
        float val = 2.0f * REST_RHO * (vdj.y - L.w) * vdj.x;
        sgx += val * gx;
        sgy += val * gy;
    }
    sgx = group_sum(sgx); sgy = group_sum(sgy);
    if (sl == 0) g[node] = make_float2(sgx, sgy);
}

// Pass 4: one gather per edge (g[j] — cannot exist earlier); streams ej,q,dirs,vr.
template<bool USE_VR>
__global__ void k_out(const int* __restrict__ rowptr, const int* __restrict__ ej,
                      const float* __restrict__ qarr, const float2* __restrict__ dirs,
                      const float2* __restrict__ vr, const float2* __restrict__ vd,
                      const float4* __restrict__ Li4, const float2* __restrict__ g,
                      float* __restrict__ out, int N) {
    int tid  = blockIdx.x * blockDim.x + threadIdx.x;
    int node = tid / LPN;
    int sl   = tid % LPN;
    if (node >= N) return;
    int beg = rowptr[node], end = rowptr[node + 1];
    float  rho_i = Li4[node].w;    // broadcast
    float2 gi    = g[node];        // broadcast

    float s = 0.f;
    for (int e = beg + sl; e < end; e += LPN) {
        int jj = ej[e];
        float q = qarr[e];
        float2 d = dirs[e];
        float2 vdj = USE_VR ? vr[e] : vd[jj];
        float2 gj  = g[jj];                       // the one unavoidable gather
        float w = wendland_dkdq(q) * INV_H3;
        float gwx = d.x * w, gwy = d.y * w;
        float rx = -d.x * q * H, ry = -d.y * q * H;
        float rji2 = rx * rx + ry * ry + EPS_REF;
        float gradTerm = (gwx * rx + gwy * ry) / rji2;
        float densityTerm = 0.5f * ((gi.x + gj.x) * rx + (gi.y + gj.y) * ry);
        float rho_ba = REST_RHO * (vdj.y - rho_i);
        s += (rho_ba + densityTerm) * gradTerm * vdj.x;
    }
    s = group_sum(s);
    if (sl == 0) out[node] = s * K_OUT;
}

extern "C" void kernel_launch(void* const* d_in, const int* in_sizes, int n_in,
                              void* d_out, int out_size, void* d_ws, size_t ws_size,
                              hipStream_t stream) {
    // inputs: 0 fluidPosition (unused), 1 fluidVolume[N], 2 fluidDensity[N],
    //         3 distances[E,2], 4 radialDistances[E], 5 i[E], 6 j[E]
    const float*  vol  = (const float*)d_in[1];
    const float*  dens = (const float*)d_in[2];
    const float2* dirs = (const float2*)d_in[3];
    const float*  qarr = (const float*)d_in[4];
    const int*    ei   = (const int*)d_in[5];
    const int*    ej   = (const int*)d_in[6];
    const int N = in_sizes[1];
    const int E = in_sizes[4];

    // ws layout: rowptr int[N+1] | vd float2[N] | Li4 float4[N] | g float2[N] | vr float2[E]
    char*   p      = (char*)d_ws;
    int*    rowptr = (int*)p;            p += (((size_t)(N + 1) * 4) + 15) & ~(size_t)15;
    float2* vd     = (float2*)p;         p += (size_t)N * sizeof(float2);
    float4* Li4    = (float4*)p;         p += (size_t)N * sizeof(float4);
    float2* g      = (float2*)p;         p += (size_t)N * sizeof(float2);
    float2* vr     = (float2*)p;         p += (size_t)E * sizeof(float2);
    const bool use_vr = ((size_t)(p - (char*)d_ws) <= ws_size);  // host-constant branch
    float*  out    = (float*)d_out;

    const int tb = 256;
    const int gP = (E + 1 + tb - 1) / tb;                 // prep (covers N too: E >> N)
    const int gN = ((size_t)N * LPN + tb - 1) / tb;       // node kernels

    k_prep<<<gP, tb, 0, stream>>>(ei, vol, dens, rowptr, vd, N, E);
    if (use_vr) {
        k_M_pinv <true><<<gN, tb, 0, stream>>>(rowptr, ej, qarr, dirs, vd, vr, Li4, N);
        k_gradRho<true><<<gN, tb, 0, stream>>>(rowptr, ej, qarr, dirs, vr, vd, Li4, g, N);
        k_out    <true><<<gN, tb, 0, stream>>>(rowptr, ej, qarr, dirs, vr, vd, Li4, g, out, N);
    } else {
        k_M_pinv <false><<<gN, tb, 0, stream>>>(rowptr, ej, qarr, dirs, vd, vr, Li4, N);
        k_gradRho<false><<<gN, tb, 0, stream>>>(rowptr, ej, qarr, dirs, vr, vd, Li4, g, N);
        k_out    <false><<<gN, tb, 0, stream>>>(rowptr, ej, qarr, dirs, vr, vd, Li4, g, out, N);
    }
}

// Round 5
// 254.988 us; speedup vs baseline: 1.2094x; 1.1945x over previous
//
#include <hip/hip_runtime.h>
#include <hip/hip_fp16.h>
#include <math.h>

#define WAVE 64

// ---- constants from the reference ----
#define KC        2.2281692032865347f   // 7/pi
#define H         0.05f
#define INV_H2    400.0f                // 1/h^2
#define INV_H3    8000.0f               // 1/h^3
#define EPS_REF   0.00025f              // h^2 * 0.1
#define K_OUT     0.24261080f           // 2*h*DELTA*C0
#define REST_RHO  1000.0f

__device__ __forceinline__ float wendland_dkdq(float q) {
    float omq = 1.0f - q;
    return -20.0f * q * omq * omq * omq * KC;
}

union H2F { __half2 h; float f; };
__device__ __forceinline__ float   h2_as_f(__half2 h) { H2F u; u.h = h; return u.f; }
__device__ __forceinline__ __half2 f_as_h2(float f)   { H2F u; u.f = f; return u.h; }

// ---------------------------------------------------------------------------
// 4-edge-per-lane segmented reduction into base[key*NV+c]. Keys sorted asc.
// (verbatim from round 2 — correctness-proven)
// ---------------------------------------------------------------------------
template<int NV>
__device__ __forceinline__ void seg_reduce4(const int k[4], float v[4][NV],
                                            float* __restrict__ base) {
    const int lane = threadIdx.x & (WAVE - 1);
    const int k0 = k[0], k3 = k[3];
    const bool split = (k0 != k3);
    const int firstLen  = (k[1]==k0) ? ((k[2]==k0) ? ((k[3]==k0)?4:3) : 2) : 1;
    const int lastStart = (k[2]==k3) ? ((k[1]==k3) ? ((k[0]==k3)?0:1) : 2) : 3;

    float vin[NV], vfirst[NV];
#pragma unroll
    for (int c = 0; c < NV; ++c) {
        float s = v[3][c];
        if (lastStart <= 2) s += v[2][c];
        if (lastStart <= 1) s += v[1][c];
        if (lastStart == 0) s += v[0][c];
        vin[c] = s;
        float f = v[0][c];
        if (firstLen >= 2) f += v[1][c];
        if (firstLen >= 3) f += v[2][c];
        if (firstLen >= 4) f += v[3][c];
        vfirst[c] = f;
    }
#pragma unroll
    for (int idx = 1; idx <= 2; ++idx) {
        if (idx >= firstLen && idx < lastStart && k[idx] >= 0) {
#pragma unroll
            for (int c = 0; c < NV; ++c)
                atomicAdd(base + (size_t)k[idx] * NV + c, v[idx][c]);
        }
    }
    float S[NV];
#pragma unroll
    for (int c = 0; c < NV; ++c) S[c] = vin[c];
    const int klast = k3;
#pragma unroll
    for (int d = 1; d < WAVE; d <<= 1) {
        int okey = __shfl_up(klast, d, WAVE);
        float ov[NV];
#pragma unroll
        for (int c = 0; c < NV; ++c) ov[c] = __shfl_up(S[c], d, WAVE);
        if (lane >= d && okey == klast) {
#pragma unroll
            for (int c = 0; c < NV; ++c) S[c] += ov[c];
        }
    }
    const int prevk = __shfl_up(klast, 1, WAVE);
    float P[NV];
#pragma unroll
    for (int c = 0; c < NV; ++c) P[c] = __shfl_up(S[c], 1, WAVE);
    if (split && k0 >= 0) {
        const bool carry = (lane > 0 && prevk == k0);
#pragma unroll
        for (int c = 0; c < NV; ++c)
            atomicAdd(base + (size_t)k0 * NV + c, vfirst[c] + (carry ? P[c] : 0.f));
    }
    const int nk0 = __shfl_down(k0, 1, WAVE);
    const bool tail = (lane == WAVE - 1) || (nk0 != klast);
    if (tail && klast >= 0) {
#pragma unroll
        for (int c = 0; c < NV; ++c)
            atomicAdd(base + (size_t)klast * NV + c, S[c]);
    }
}

// pack vd = (vol, dens)
__global__ void k_init(const float* __restrict__ vol, const float* __restrict__ dens,
                       float2* __restrict__ vd, int N) {
    int n = blockIdx.x * blockDim.x + threadIdx.x;
    if (n < N) vd[n] = make_float2(vol[n], dens[n]);
}

// Pass A: the ONLY vd[j] gather in the pipeline. Accumulate M (atomics via
// seg scan) and stream out half-compressed per-edge records ehd,vr.
template<bool FULL>
__global__ void k_A(const int* __restrict__ ei, const int* __restrict__ ej,
                    const float* __restrict__ qarr, const float2* __restrict__ dirs,
                    const float2* __restrict__ vd, __half2* __restrict__ ehd,
                    __half2* __restrict__ vr, float* __restrict__ M, int E) {
    int t = blockIdx.x * blockDim.x + threadIdx.x;
    long e0 = 4L * t;
    int k[4]; float v[4][3];
    if (e0 + 3 < (long)E) {
        int4   i4 = ((const int4*)ei)[t];
        int4   j4 = ((const int4*)ej)[t];
        float4 q4 = ((const float4*)qarr)[t];
        float4 dA = ((const float4*)dirs)[2 * t];
        float4 dB = ((const float4*)dirs)[2 * t + 1];
        int   iv[4] = {i4.x, i4.y, i4.z, i4.w};
        int   jv[4] = {j4.x, j4.y, j4.z, j4.w};
        float qv[4] = {q4.x, q4.y, q4.z, q4.w};
        float dxv[4] = {dA.x, dA.z, dB.x, dB.z};
        float dyv[4] = {dA.y, dA.w, dB.y, dB.w};
        float2 vdj[4];
#pragma unroll
        for (int u = 0; u < 4; ++u) vdj[u] = vd[jv[u]];   // 4 independent gathers
        float4 ehp, vrp;
#pragma unroll
        for (int u = 0; u < 4; ++u) {
            float rhoi = vd[iv[u]].y;                     // broadcast-class load
            float q = qv[u], dx = dxv[u], dy = dyv[u];
            float Vj = vdj[u].x;
            float dro = vdj[u].y - rhoi;                  // fp32: no cancellation loss
            float s = -2.0f * Vj * q * wendland_dkdq(q) * INV_H2;   // >= 0
            k[u] = iv[u];
            v[u][0] = s * dx * dx; v[u][1] = s * dx * dy; v[u][2] = s * dy * dy;
            if (FULL) {
                (&ehp.x)[u] = h2_as_f(__floats2half2_rn(dx, dy));
                (&vrp.x)[u] = h2_as_f(__floats2half2_rn(Vj, dro));
            }
        }
        if (FULL) {
            ((float4*)ehd)[t] = ehp;   // coalesced 16B stores
            ((float4*)vr)[t]  = vrp;
        }
    } else {
        int lastk = -1;
#pragma unroll
        for (int u = 0; u < 4; ++u) {
            long e = e0 + u;
            if (e < (long)E) {
                int ii = ei[e], jj = ej[e];
                float q = qarr[e];
                float2 d = dirs[e];
                float2 vdj = vd[jj];
                float dro = vdj.y - vd[ii].y;
                float s = -2.0f * vdj.x * q * wendland_dkdq(q) * INV_H2;
                k[u] = ii;
                v[u][0] = s * d.x * d.x; v[u][1] = s * d.x * d.y; v[u][2] = s * d.y * d.y;
                if (FULL) {
                    ehd[e] = __floats2half2_rn(d.x, d.y);
                    vr[e]  = __floats2half2_rn(vdj.x, dro);
                }
                lastk = ii;
            } else {
                k[u] = lastk; v[u][0] = v[u][1] = v[u][2] = 0.f;
            }
        }
    }
    seg_reduce4<3>(k, v, M);
}

// Pass B: symmetric PSD 2x2 pinv, JAX cutoff semantics. Li4=(i00,i01,i11,0).
__global__ void k_pinv(const float* __restrict__ M, float4* __restrict__ Li4, int N) {
    int n = blockIdx.x * blockDim.x + threadIdx.x;
    if (n >= N) return;
    float a = M[3*n+0], b = M[3*n+1], c = M[3*n+2];
    float half_tr   = 0.5f * (a + c);
    float half_diff = 0.5f * (a - c);
    float disc = sqrtf(half_diff * half_diff + b * b);
    float l1 = half_tr + disc, l2 = half_tr - disc;
    float smax = fmaxf(fabsf(l1), fabsf(l2));
    float cutoff = 2.3841858e-6f * smax;   // rcond = 10*max(2,2)*eps_f32
    float i00 = 0.f, i01 = 0.f, i11 = 0.f;
    if (fabsf(l2) > cutoff) {
        float inv = 1.0f / (a * c - b * b);
        i00 =  c * inv; i01 = -b * inv; i11 = a * inv;
    } else if (fabsf(l1) > cutoff) {
        float vax = b,      vay = l1 - a;
        float vbx = l1 - c, vby = b;
        float na = vax*vax + vay*vay, nb = vbx*vbx + vby*vby;
        float vx, vy, n2;
        if (nb >= na) { vx = vbx; vy = vby; n2 = nb; }
        else          { vx = vax; vy = vay; n2 = na; }
        float inv = 1.0f / (l1 * n2);
        i00 = vx*vx*inv; i01 = vx*vy*inv; i11 = vy*vy*inv;
    }
    Li4[n] = make_float4(i00, i01, i11, 0.f);
}

// Pass C: pure streaming (FULL) — i4,q4,ehd,vr all via 16B loads; Li4[i] broadcast.
template<bool FULL>
__global__ void k_C(const int* __restrict__ ei, const int* __restrict__ ej,
                    const float* __restrict__ qarr, const float2* __restrict__ dirs,
                    const __half2* __restrict__ ehd, const __half2* __restrict__ vr,
                    const float2* __restrict__ vd, const float4* __restrict__ Li4,
                    float* __restrict__ g, int E) {
    int t = blockIdx.x * blockDim.x + threadIdx.x;
    long e0 = 4L * t;
    int k[4]; float v[4][2];
    if (e0 + 3 < (long)E) {
        int4   i4 = ((const int4*)ei)[t];
        float4 q4 = ((const float4*)qarr)[t];
        int   iv[4] = {i4.x, i4.y, i4.z, i4.w};
        float qv[4] = {q4.x, q4.y, q4.z, q4.w};
        float dxv[4], dyv[4], Vjv[4], drov[4];
        if (FULL) {
            float4 es = ((const float4*)ehd)[t];
            float4 vs = ((const float4*)vr)[t];
#pragma unroll
            for (int u = 0; u < 4; ++u) {
                __half2 hd = f_as_h2((&es.x)[u]);
                __half2 hv = f_as_h2((&vs.x)[u]);
                dxv[u] = __low2float(hd);  dyv[u] = __high2float(hd);
                Vjv[u] = __low2float(hv);  drov[u] = __high2float(hv);
            }
        } else {
            int4   j4 = ((const int4*)ej)[t];
            float4 dA = ((const float4*)dirs)[2 * t];
            float4 dB = ((const float4*)dirs)[2 * t + 1];
            int jv[4] = {j4.x, j4.y, j4.z, j4.w};
            dxv[0]=dA.x; dyv[0]=dA.y; dxv[1]=dA.z; dyv[1]=dA.w;
            dxv[2]=dB.x; dyv[2]=dB.y; dxv[3]=dB.z; dyv[3]=dB.w;
#pragma unroll
            for (int u = 0; u < 4; ++u) {
                float2 vdj = vd[jv[u]];
                Vjv[u] = vdj.x; drov[u] = vdj.y - vd[iv[u]].y;
            }
        }
#pragma unroll
        for (int u = 0; u < 4; ++u) {
            int key = iv[u]; k[u] = key;
            float q = qv[u];
            float w = wendland_dkdq(q) * INV_H3;
            float gwx = dxv[u] * w, gwy = dyv[u] * w;
            float4 L = Li4[key];                        // broadcast-class load
            float gx = L.x * gwx + L.y * gwy;
            float gy = L.y * gwx + L.z * gwy;
            float dwij_mag = fabsf(gwx) + fabsf(gwy);
            float norm_mag = fabsf(gx) + fabsf(gy);
            float change = fabsf(norm_mag - dwij_mag) / (dwij_mag + 1e-4f * H);
            if (!(change < 0.1f)) { gx = gwx; gy = gwy; }   // NaN -> fallback
            float val = 2.0f * REST_RHO * drov[u] * Vjv[u];
            v[u][0] = val * gx;
            v[u][1] = val * gy;
        }
    } else {
        int lastk = -1;
#pragma unroll
        for (int u = 0; u < 4; ++u) {
            long e = e0 + u;
            v[u][0] = v[u][1] = 0.f;
            if (e < (long)E) {
                int key = ei[e]; lastk = key; k[u] = key;
                float q = qarr[e];
                float dx, dy, Vj, dro;
                if (FULL) {
                    __half2 hd = ehd[e], hv = vr[e];
                    dx = __low2float(hd); dy = __high2float(hd);
                    Vj = __low2float(hv); dro = __high2float(hv);
                } else {
                    float2 d = dirs[e]; dx = d.x; dy = d.y;
                    float2 vdj = vd[ej[e]];
                    Vj = vdj.x; dro = vdj.y - vd[key].y;
                }
                float w = wendland_dkdq(q) * INV_H3;
                float gwx = dx * w, gwy = dy * w;
                float4 L = Li4[key];
                float gx = L.x * gwx + L.y * gwy;
                float gy = L.y * gwx + L.z * gwy;
                float dwij_mag = fabsf(gwx) + fabsf(gwy);
                float norm_mag = fabsf(gx) + fabsf(gy);
                float change = fabsf(norm_mag - dwij_mag) / (dwij_mag + 1e-4f * H);
                if (!(change < 0.1f)) { gx = gwx; gy = gwy; }
                float val = 2.0f * REST_RHO * dro * Vj;
                v[u][0] = val * gx; v[u][1] = val * gy;
            } else k[u] = lastk;
        }
    }
    seg_reduce4<2>(k, v, g);
}

// Pass D: one unavoidable gather class (g[j]); everything else streamed.
template<bool FULL>
__global__ void k_D(const int* __restrict__ ei, const int* __restrict__ ej,
                    const float* __restrict__ qarr, const float2* __restrict__ dirs,
                    const __half2* __restrict__ ehd, const __half2* __restrict__ vr,
                    const float2* __restrict__ vd, const float2* __restrict__ g,
                    float* __restrict__ out, int E) {
    int t = blockIdx.x * blockDim.x + threadIdx.x;
    long e0 = 4L * t;
    int k[4]; float v[4][1];
    if (e0 + 3 < (long)E) {
        int4   i4 = ((const int4*)ei)[t];
        int4   j4 = ((const int4*)ej)[t];
        float4 q4 = ((const float4*)qarr)[t];
        int   iv[4] = {i4.x, i4.y, i4.z, i4.w};
        int   jv[4] = {j4.x, j4.y, j4.z, j4.w};
        float qv[4] = {q4.x, q4.y, q4.z, q4.w};
        float dxv[4], dyv[4], Vjv[4], drov[4];
        if (FULL) {
            float4 es = ((const float4*)ehd)[t];
            float4 vs = ((const float4*)vr)[t];
#pragma unroll
            for (int u = 0; u < 4; ++u) {
                __half2 hd = f_as_h2((&es.x)[u]);
                __half2 hv = f_as_h2((&vs.x)[u]);
                dxv[u] = __low2float(hd);  dyv[u] = __high2float(hd);
                Vjv[u] = __low2float(hv);  drov[u] = __high2float(hv);
            }
        } else {
            float4 dA = ((const float4*)dirs)[2 * t];
            float4 dB = ((const float4*)dirs)[2 * t + 1];
            dxv[0]=dA.x; dyv[0]=dA.y; dxv[1]=dA.z; dyv[1]=dA.w;
            dxv[2]=dB.x; dyv[2]=dB.y; dxv[3]=dB.z; dyv[3]=dB.w;
#pragma unroll
            for (int u = 0; u < 4; ++u) {
                float2 vdj = vd[jv[u]];
                Vjv[u] = vdj.x; drov[u] = vdj.y - vd[iv[u]].y;
            }
        }
        float2 gjv[4];
#pragma unroll
        for (int u = 0; u < 4; ++u) gjv[u] = g[jv[u]];   // 4 independent gathers
#pragma unroll
        for (int u = 0; u < 4; ++u) {
            int key = iv[u]; k[u] = key;
            float2 gi = g[key];                           // broadcast-class load
            float q = qv[u];
            float w = wendland_dkdq(q) * INV_H3;
            float gwx = dxv[u] * w, gwy = dyv[u] * w;
            float rx = -dxv[u] * q * H, ry = -dyv[u] * q * H;
            float rji2 = rx * rx + ry * ry + EPS_REF;
            float gradTerm = (gwx * rx + gwy * ry) / rji2;
            float densityTerm = 0.5f * ((gi.x + gjv[u].x) * rx + (gi.y + gjv[u].y) * ry);
            float rho_ba = REST_RHO * drov[u];
            v[u][0] = (rho_ba + densityTerm) * gradTerm * Vjv[u] * K_OUT;
        }
    } else {
        int lastk = -1;
#pragma unroll
        for (int u = 0; u < 4; ++u) {
            long e = e0 + u;
            v[u][0] = 0.f;
            if (e < (long)E) {
                int key = ei[e], jj = ej[e]; lastk = key; k[u] = key;
                float q = qarr[e];
                float dx, dy, Vj, dro;
                if (FULL) {
                    __half2 hd = ehd[e], hv = vr[e];
                    dx = __low2float(hd); dy = __high2float(hd);
                    Vj = __low2float(hv); dro = __high2float(hv);
                } else {
                    float2 d = dirs[e]; dx = d.x; dy = d.y;
                    float2 vdj = vd[jj];
                    Vj = vdj.x; dro = vdj.y - vd[key].y;
                }
                float2 gi = g[key], gj = g[jj];
                float w = wendland_dkdq(q) * INV_H3;
                float gwx = dx * w, gwy = dy * w;
                float rx = -dx * q * H, ry = -dy * q * H;
                float rji2 = rx * rx + ry * ry + EPS_REF;
                float gradTerm = (gwx * rx + gwy * ry) / rji2;
                float densityTerm = 0.5f * ((gi.x + gj.x) * rx + (gi.y + gj.y) * ry);
                float rho_ba = REST_RHO * dro;
                v[u][0] = (rho_ba + densityTerm) * gradTerm * Vj * K_OUT;
            } else k[u] = lastk;
        }
    }
    seg_reduce4<1>(k, v, out);
}

extern "C" void kernel_launch(void* const* d_in, const int* in_sizes, int n_in,
                              void* d_out, int out_size, void* d_ws, size_t ws_size,
                              hipStream_t stream) {
    const float*  vol  = (const float*)d_in[1];
    const float*  dens = (const float*)d_in[2];
    const float2* dirs = (const float2*)d_in[3];
    const float*  qarr = (const float*)d_in[4];
    const int*    ei   = (const int*)d_in[5];
    const int*    ej   = (const int*)d_in[6];
    const int N = in_sizes[1];
    const int E = in_sizes[4];

    // ws: vd f2[N] | M f[3N] | Li4 f4[N] | ehd h2[E] | vr h2[E]  (58.4 MB @ given sizes)
    size_t off = 0;
    auto alloc = [&](size_t bytes) { void* r = (char*)d_ws + off;
                                     off = (off + bytes + 15) & ~(size_t)15; return r; };
    float2*  vd  = (float2*) alloc((size_t)N * 8);
    float*   M   = (float*)  alloc((size_t)N * 12);
    float4*  Li4 = (float4*) alloc((size_t)N * 16);
    __half2* ehd = (__half2*)alloc((size_t)E * 4);
    __half2* vr  = (__half2*)alloc((size_t)E * 4);
    const bool full = (off <= ws_size);          // host-constant branch
    float2*  g   = full ? vd : (float2*)M;       // overlay: vd dead after A, M after B
    float*   out = (float*)d_out;

    const int tb = 256;
    const int gN = (N + tb - 1) / tb;
    const int gT = ((E + 3) / 4 + tb - 1) / tb;

    k_init<<<gN, tb, 0, stream>>>(vol, dens, vd, N);
    hipMemsetAsync(M, 0, (size_t)N * 12, stream);
    hipMemsetAsync(out, 0, (size_t)N * 4, stream);
    if (full) {
        k_A<true><<<gT, tb, 0, stream>>>(ei, ej, qarr, dirs, vd, ehd, vr, M, E);
        k_pinv<<<gN, tb, 0, stream>>>(M, Li4, N);
        hipMemsetAsync(g, 0, (size_t)N * 8, stream);
        k_C<true><<<gT, tb, 0, stream>>>(ei, ej, qarr, dirs, ehd, vr, vd, Li4, (float*)g, E);
        k_D<true><<<gT, tb, 0, stream>>>(ei, ej, qarr, dirs, ehd, vr, vd, g, out, E);
    } else {
        k_A<false><<<gT, tb, 0, stream>>>(ei, ej, qarr, dirs, vd, ehd, vr, M, E);
        k_pinv<<<gN, tb, 0, stream>>>(M, Li4, N);
        hipMemsetAsync(g, 0, (size_t)N * 8, stream);
        k_C<false><<<gT, tb, 0, stream>>>(ei, ej, qarr, dirs, ehd, vr, vd, Li4, (float*)g, E);
        k_D<false><<<gT, tb, 0, stream>>>(ei, ej, qarr, dirs, ehd, vr, vd, g, out, E);
    }
}

// Round 6
// 247.176 us; speedup vs baseline: 1.2476x; 1.0316x over previous
//
#include <hip/hip_runtime.h>
#include <math.h>

#define WAVE   64
#define NPB    32          // nodes per block
#define BLOCKT 256
#define SMAX   2           // stashed 1024-edge chunks (covers <=2048 edges/window)

// ---- constants from the reference ----
#define KC        2.2281692032865347f   // 7/pi
#define H         0.05f
#define INV_H2    400.0f
#define INV_H3    8000.0f
#define EPS_REF   0.00025f              // h^2 * 0.1
#define K_OUT     0.24261080f           // 2*h*DELTA*C0
#define REST_RHO  1000.0f

__device__ __forceinline__ float wendland_dkdq(float q) {
    float o = 1.f - q;
    return -20.f * q * o * o * o * KC;
}

// ---------------------------------------------------------------------------
// 4-edge-per-lane segmented reduction (proven in R2/R5). Only requirement:
// equal keys contiguous in lane order; key<0 entries are skipped at flush.
// base may be an LDS array (atomicAdd -> ds_add_f32 after inlining).
// ---------------------------------------------------------------------------
template<int NV>
__device__ __forceinline__ void seg_reduce4(const int k[4], float v[4][NV], float* base) {
    const int lane = threadIdx.x & (WAVE - 1);
    const int k0 = k[0], k3 = k[3];
    const bool split = (k0 != k3);
    const int firstLen  = (k[1]==k0) ? ((k[2]==k0) ? ((k[3]==k0)?4:3) : 2) : 1;
    const int lastStart = (k[2]==k3) ? ((k[1]==k3) ? ((k[0]==k3)?0:1) : 2) : 3;

    float vin[NV], vfirst[NV];
#pragma unroll
    for (int c = 0; c < NV; ++c) {
        float s = v[3][c];
        if (lastStart <= 2) s += v[2][c];
        if (lastStart <= 1) s += v[1][c];
        if (lastStart == 0) s += v[0][c];
        vin[c] = s;
        float f = v[0][c];
        if (firstLen >= 2) f += v[1][c];
        if (firstLen >= 3) f += v[2][c];
        if (firstLen >= 4) f += v[3][c];
        vfirst[c] = f;
    }
#pragma unroll
    for (int idx = 1; idx <= 2; ++idx) {
        if (idx >= firstLen && idx < lastStart && k[idx] >= 0) {
#pragma unroll
            for (int c = 0; c < NV; ++c)
                atomicAdd(base + (size_t)k[idx] * NV + c, v[idx][c]);
        }
    }
    float S[NV];
#pragma unroll
    for (int c = 0; c < NV; ++c) S[c] = vin[c];
    const int klast = k3;
#pragma unroll
    for (int d = 1; d < WAVE; d <<= 1) {
        int okey = __shfl_up(klast, d, WAVE);
        float ov[NV];
#pragma unroll
        for (int c = 0; c < NV; ++c) ov[c] = __shfl_up(S[c], d, WAVE);
        if (lane >= d && okey == klast) {
#pragma unroll
            for (int c = 0; c < NV; ++c) S[c] += ov[c];
        }
    }
    const int prevk = __shfl_up(klast, 1, WAVE);
    float P[NV];
#pragma unroll
    for (int c = 0; c < NV; ++c) P[c] = __shfl_up(S[c], 1, WAVE);
    if (split && k0 >= 0) {
        const bool carry = (lane > 0 && prevk == k0);
#pragma unroll
        for (int c = 0; c < NV; ++c)
            atomicAdd(base + (size_t)k0 * NV + c, vfirst[c] + (carry ? P[c] : 0.f));
    }
    const int nk0 = __shfl_down(k0, 1, WAVE);
    const bool tail = (lane == WAVE - 1) || (nk0 != klast);
    if (tail && klast >= 0) {
#pragma unroll
        for (int c = 0; c < NV; ++c)
            atomicAdd(base + (size_t)klast * NV + c, S[c]);
    }
}

struct EW { int iv[4], jv[4]; float qv[4], dxv[4], dyv[4]; bool okv[4]; };

__device__ __forceinline__ void load_win(long e0, int beg, int end, int E,
        const int* __restrict__ ei, const int* __restrict__ ej,
        const float* __restrict__ qarr, const float2* __restrict__ dirs, EW& w) {
    if (e0 + 3 < (long)E) {
        int4   i4 = *(const int4*)(ei + e0);
        int4   j4 = *(const int4*)(ej + e0);
        float4 q4 = *(const float4*)(qarr + e0);
        float4 dA = *(const float4*)((const float*)dirs + 2 * e0);
        float4 dB = *(const float4*)((const float*)dirs + 2 * e0 + 4);
        w.iv[0]=i4.x; w.iv[1]=i4.y; w.iv[2]=i4.z; w.iv[3]=i4.w;
        w.jv[0]=j4.x; w.jv[1]=j4.y; w.jv[2]=j4.z; w.jv[3]=j4.w;
        w.qv[0]=q4.x; w.qv[1]=q4.y; w.qv[2]=q4.z; w.qv[3]=q4.w;
        w.dxv[0]=dA.x; w.dyv[0]=dA.y; w.dxv[1]=dA.z; w.dyv[1]=dA.w;
        w.dxv[2]=dB.x; w.dyv[2]=dB.y; w.dxv[3]=dB.z; w.dyv[3]=dB.w;
    } else {
#pragma unroll
        for (int u = 0; u < 4; ++u) {
            long e = e0 + u;
            if (e < (long)E) {
                w.iv[u] = ei[e]; w.jv[u] = ej[e]; w.qv[u] = qarr[e];
                float2 d = dirs[e]; w.dxv[u] = d.x; w.dyv[u] = d.y;
            } else { w.iv[u]=0; w.jv[u]=0; w.qv[u]=0.f; w.dxv[u]=0.f; w.dyv[u]=0.f; }
        }
    }
#pragma unroll
    for (int u = 0; u < 4; ++u) {
        long e = e0 + u;
        w.okv[u] = (e >= (long)beg) && (e < (long)end) && (e < (long)E);
    }
}

// rowptr[t] = first edge e with i[e] >= t (i sorted); also pack vd=(vol,dens).
__global__ void k_prep(const int* __restrict__ ei, const float* __restrict__ vol,
                       const float* __restrict__ dens, int* __restrict__ rowptr,
                       float2* __restrict__ vd, int N, int E) {
    int e = blockIdx.x * blockDim.x + threadIdx.x;
    if (e <= E) {
        int prev = (e == 0) ? -1 : ei[e - 1];
        int cur  = (e == E) ? N  : ei[e];
        for (int t = prev + 1; t <= cur; ++t) rowptr[t] = e;
    }
    if (e < N) vd[e] = make_float2(vol[e], dens[e]);
}

// Fused A+B+C: per block, M-sweep -> pinv -> gradRho-sweep, all node-local.
// Writes nd[n] = (vol, dens, gradRho.x, gradRho.y). No global atomics.
__global__ __launch_bounds__(BLOCKT, 4)
void k_AC(const int* __restrict__ ei, const int* __restrict__ ej,
          const float* __restrict__ qarr, const float2* __restrict__ dirs,
          const float2* __restrict__ vd, const int* __restrict__ rowptr,
          float4* __restrict__ nd, int N, int E) {
    __shared__ float  Mld[NPB * 3];
    __shared__ float  Lild[NPB * 3];
    __shared__ float  gld[NPB * 2];
    __shared__ float2 vdl[NPB];
    const int tid = threadIdx.x;
    const int n0  = blockIdx.x * NPB;
    const int nHi = min(n0 + NPB, N);
    if (tid < NPB && n0 + tid < N) vdl[tid] = vd[n0 + tid];
    if (tid < NPB * 3) Mld[tid] = 0.f;
    if (tid < NPB * 2) gld[tid] = 0.f;
    __syncthreads();
    const int  beg  = rowptr[n0], end = rowptr[nHi];
    const long beg4 = (long)beg & ~3L;
    const int  waveBase = tid & ~(WAVE - 1);

    int   li_s[4 * SMAX];
    float w_s[4 * SMAX], dx_s[4 * SMAX], dy_s[4 * SMAX], val_s[4 * SMAX];
#pragma unroll
    for (int x = 0; x < 4 * SMAX; ++x) { li_s[x] = -1; w_s[x]=dx_s[x]=dy_s[x]=val_s[x]=0.f; }

    // ---- phase 1: M accumulation (stashed chunks) ----
#pragma unroll
    for (int c = 0; c < SMAX; ++c) {
        long ebw = beg4 + ((long)c * BLOCKT + waveBase) * 4;
        if (ebw < (long)end) {
            long e0 = beg4 + ((long)c * BLOCKT + tid) * 4;
            EW wd; load_win(e0, beg, end, E, ei, ej, qarr, dirs, wd);
            int k[4]; float v[4][3];
#pragma unroll
            for (int u = 0; u < 4; ++u) {
                k[u] = -1; v[u][0] = v[u][1] = v[u][2] = 0.f;
                if (wd.okv[u]) {
                    int li = wd.iv[u] - n0;
                    float q = wd.qv[u], dx = wd.dxv[u], dy = wd.dyv[u];
                    float2 vdj = vd[wd.jv[u]];
                    float wq = wendland_dkdq(q);
                    float s = -2.f * vdj.x * q * wq * INV_H2;   // >= 0
                    k[u] = li;
                    v[u][0] = s * dx * dx; v[u][1] = s * dx * dy; v[u][2] = s * dy * dy;
                    li_s[c*4+u] = li; w_s[c*4+u] = wq * INV_H3;
                    dx_s[c*4+u] = dx; dy_s[c*4+u] = dy;
                    val_s[c*4+u] = 2.f * REST_RHO * (vdj.y - vdl[li].y) * vdj.x;
                }
            }
            seg_reduce4<3>(k, v, Mld);
        }
    }
    // overflow chunks (window > SMAX*1024 edges; never hit at E/N=32 avg degree)
    for (int c = SMAX; ; ++c) {
        long ebw = beg4 + ((long)c * BLOCKT + waveBase) * 4;
        if (ebw >= (long)end) break;
        long e0 = beg4 + ((long)c * BLOCKT + tid) * 4;
        EW wd; load_win(e0, beg, end, E, ei, ej, qarr, dirs, wd);
        int k[4]; float v[4][3];
#pragma unroll
        for (int u = 0; u < 4; ++u) {
            k[u] = -1; v[u][0] = v[u][1] = v[u][2] = 0.f;
            if (wd.okv[u]) {
                int li = wd.iv[u] - n0;
                float q = wd.qv[u], dx = wd.dxv[u], dy = wd.dyv[u];
                float2 vdj = vd[wd.jv[u]];
                float s = -2.f * vdj.x * q * wendland_dkdq(q) * INV_H2;
                k[u] = li;
                v[u][0] = s * dx * dx; v[u][1] = s * dx * dy; v[u][2] = s * dy * dy;
            }
        }
        seg_reduce4<3>(k, v, Mld);
    }
    __syncthreads();

    // ---- pinv (one lane per node), JAX cutoff semantics ----
    if (tid < NPB) {
        float a = Mld[3*tid], b = Mld[3*tid+1], cc = Mld[3*tid+2];
        float half_tr   = 0.5f * (a + cc);
        float half_diff = 0.5f * (a - cc);
        float disc = sqrtf(half_diff * half_diff + b * b);
        float l1 = half_tr + disc, l2 = half_tr - disc;
        float smax = fmaxf(fabsf(l1), fabsf(l2));
        float cutoff = 2.3841858e-6f * smax;   // rcond = 10*max(2,2)*eps_f32
        float i00 = 0.f, i01 = 0.f, i11 = 0.f;
        if (fabsf(l2) > cutoff) {
            float inv = 1.0f / (a * cc - b * b);
            i00 =  cc * inv; i01 = -b * inv; i11 = a * inv;
        } else if (fabsf(l1) > cutoff) {
            float vax = b,       vay = l1 - a;
            float vbx = l1 - cc, vby = b;
            float na = vax*vax + vay*vay, nb = vbx*vbx + vby*vby;
            float vx, vy, n2;
            if (nb >= na) { vx = vbx; vy = vby; n2 = nb; }
            else          { vx = vax; vy = vay; n2 = na; }
            float inv = 1.0f / (l1 * n2);
            i00 = vx*vx*inv; i01 = vx*vy*inv; i11 = vy*vy*inv;
        }
        Lild[3*tid] = i00; Lild[3*tid+1] = i01; Lild[3*tid+2] = i11;
    }
    __syncthreads();

    // ---- phase 2: gradRho from stash ----
#pragma unroll
    for (int c = 0; c < SMAX; ++c) {
        long ebw = beg4 + ((long)c * BLOCKT + waveBase) * 4;
        if (ebw < (long)end) {
            int k[4]; float v[4][2];
#pragma unroll
            for (int u = 0; u < 4; ++u) {
                int li = li_s[c*4+u];
                k[u] = li; v[u][0] = v[u][1] = 0.f;
                if (li >= 0) {
                    float w = w_s[c*4+u], dx = dx_s[c*4+u], dy = dy_s[c*4+u];
                    float gwx = dx * w, gwy = dy * w;
                    float L0 = Lild[3*li], L1 = Lild[3*li+1], L2v = Lild[3*li+2];
                    float gx = L0 * gwx + L1 * gwy;
                    float gy = L1 * gwx + L2v * gwy;
                    float dm = fabsf(gwx) + fabsf(gwy);
                    float nm = fabsf(gx) + fabsf(gy);
                    float change = fabsf(nm - dm) / (dm + 1e-4f * H);
                    if (!(change < 0.1f)) { gx = gwx; gy = gwy; }   // NaN -> fallback
                    v[u][0] = val_s[c*4+u] * gx;
                    v[u][1] = val_s[c*4+u] * gy;
                }
            }
            seg_reduce4<2>(k, v, gld);
        }
    }
    // overflow chunks: recompute from global (rare path)
    for (int c = SMAX; ; ++c) {
        long ebw = beg4 + ((long)c * BLOCKT + waveBase) * 4;
        if (ebw >= (long)end) break;
        long e0 = beg4 + ((long)c * BLOCKT + tid) * 4;
        EW wd; load_win(e0, beg, end, E, ei, ej, qarr, dirs, wd);
        int k[4]; float v[4][2];
#pragma unroll
        for (int u = 0; u < 4; ++u) {
            k[u] = -1; v[u][0] = v[u][1] = 0.f;
            if (wd.okv[u]) {
                int li = wd.iv[u] - n0;
                float q = wd.qv[u], dx = wd.dxv[u], dy = wd.dyv[u];
                float2 vdj = vd[wd.jv[u]];
                float w = wendland_dkdq(q) * INV_H3;
                float gwx = dx * w, gwy = dy * w;
                float L0 = Lild[3*li], L1 = Lild[3*li+1], L2v = Lild[3*li+2];
                float gx = L0 * gwx + L1 * gwy;
                float gy = L1 * gwx + L2v * gwy;
                float dm = fabsf(gwx) + fabsf(gwy);
                float nm = fabsf(gx) + fabsf(gy);
                float change = fabsf(nm - dm) / (dm + 1e-4f * H);
                if (!(change < 0.1f)) { gx = gwx; gy = gwy; }
                float val = 2.f * REST_RHO * (vdj.y - vdl[li].y) * vdj.x;
                k[u] = li; v[u][0] = val * gx; v[u][1] = val * gy;
            }
        }
        seg_reduce4<2>(k, v, gld);
    }
    __syncthreads();
    if (tid < NPB && n0 + tid < N)
        nd[n0 + tid] = make_float4(vdl[tid].x, vdl[tid].y, gld[2*tid], gld[2*tid+1]);
}

// Pass D node-blocked: out written directly (no atomics, no memset).
__global__ __launch_bounds__(BLOCKT, 4)
void k_D(const int* __restrict__ ei, const int* __restrict__ ej,
         const float* __restrict__ qarr, const float2* __restrict__ dirs,
         const float4* __restrict__ nd, const int* __restrict__ rowptr,
         float* __restrict__ out, int N, int E) {
    __shared__ float4 ndl[NPB];
    __shared__ float  outl[NPB];
    const int tid = threadIdx.x;
    const int n0  = blockIdx.x * NPB;
    const int nHi = min(n0 + NPB, N);
    if (tid < NPB && n0 + tid < N) ndl[tid] = nd[n0 + tid];
    if (tid < NPB) outl[tid] = 0.f;
    __syncthreads();
    const int  beg  = rowptr[n0], end = rowptr[nHi];
    const long beg4 = (long)beg & ~3L;
    const int  waveBase = tid & ~(WAVE - 1);

    for (int c = 0; ; ++c) {
        long ebw = beg4 + ((long)c * BLOCKT + waveBase) * 4;
        if (ebw >= (long)end) break;
        long e0 = beg4 + ((long)c * BLOCKT + tid) * 4;
        EW wd; load_win(e0, beg, end, E, ei, ej, qarr, dirs, wd);
        float4 ndj[4];
#pragma unroll
        for (int u = 0; u < 4; ++u) ndj[u] = wd.okv[u] ? nd[wd.jv[u]] : make_float4(0,0,0,0);
        int k[4]; float v[4][1];
#pragma unroll
        for (int u = 0; u < 4; ++u) {
            k[u] = -1; v[u][0] = 0.f;
            if (wd.okv[u]) {
                int li = wd.iv[u] - n0;
                float4 ndi = ndl[li];
                float q = wd.qv[u], dx = wd.dxv[u], dy = wd.dyv[u];
                float w = wendland_dkdq(q) * INV_H3;
                float gwx = dx * w, gwy = dy * w;
                float rx = -dx * q * H, ry = -dy * q * H;
                float rji2 = rx * rx + ry * ry + EPS_REF;
                float gradTerm = (gwx * rx + gwy * ry) / rji2;
                float densityTerm = 0.5f * ((ndi.z + ndj[u].z) * rx + (ndi.w + ndj[u].w) * ry);
                float rho_ba = REST_RHO * (ndj[u].y - ndi.y);
                k[u] = li;
                v[u][0] = (rho_ba + densityTerm) * gradTerm * ndj[u].x;
            }
        }
        seg_reduce4<1>(k, v, outl);
    }
    __syncthreads();
    if (tid < NPB && n0 + tid < N) out[n0 + tid] = outl[tid] * K_OUT;
}

extern "C" void kernel_launch(void* const* d_in, const int* in_sizes, int n_in,
                              void* d_out, int out_size, void* d_ws, size_t ws_size,
                              hipStream_t stream) {
    const float*  vol  = (const float*)d_in[1];
    const float*  dens = (const float*)d_in[2];
    const float2* dirs = (const float2*)d_in[3];
    const float*  qarr = (const float*)d_in[4];
    const int*    ei   = (const int*)d_in[5];
    const int*    ej   = (const int*)d_in[6];
    const int N = in_sizes[1];
    const int E = in_sizes[4];

    // ws: rowptr int[N+1] | vd float2[N] | nd float4[N]
    char*   p      = (char*)d_ws;
    int*    rowptr = (int*)p;      p += (((size_t)(N + 1) * 4) + 15) & ~(size_t)15;
    float2* vd     = (float2*)p;   p += (size_t)N * sizeof(float2);
    float4* nd     = (float4*)p;
    float*  out    = (float*)d_out;

    const int tb = 256;
    const int gP = (E + 1 + tb - 1) / tb;
    const int gB = (N + NPB - 1) / NPB;

    k_prep<<<gP, tb, 0, stream>>>(ei, vol, dens, rowptr, vd, N, E);
    k_AC  <<<gB, BLOCKT, 0, stream>>>(ei, ej, qarr, dirs, vd, rowptr, nd, N, E);
    k_D   <<<gB, BLOCKT, 0, stream>>>(ei, ej, qarr, dirs, nd, rowptr, out, N, E);
}

// Round 7
// 245.452 us; speedup vs baseline: 1.2564x; 1.0070x over previous
//
#include <hip/hip_runtime.h>
#include <hip/hip_fp16.h>
#include <math.h>

#define WAVE   64
#define NPB    32          // nodes per block
#define BLOCKT 256
#define SMAX   2           // stashed 1024-edge chunks (covers <=2048 edges/window)

// ---- constants from the reference ----
#define KC        2.2281692032865347f   // 7/pi
#define H         0.05f
#define INV_H2    400.0f
#define INV_H3    8000.0f
#define EPS_REF   0.00025f              // h^2 * 0.1
#define K_OUT     0.24261080f           // 2*h*DELTA*C0
#define REST_RHO  1000.0f

__device__ __forceinline__ float wendland_dkdq(float q) {
    float o = 1.f - q;
    return -20.f * q * o * o * o * KC;
}

union H2F { __half2 h; float f; };
__device__ __forceinline__ float   h2_as_f(__half2 h) { H2F u; u.h = h; return u.f; }
__device__ __forceinline__ __half2 f_as_h2(float f)   { H2F u; u.f = f; return u.h; }

// largest li in [0,NPB) with rp[li] <= e   (rp[0] <= e < rp[NPB] guaranteed)
__device__ __forceinline__ int li_search(const int* rp, int e) {
    int lo = 0;
#pragma unroll
    for (int s = NPB / 2; s >= 1; s >>= 1) lo += (rp[lo + s] <= e) ? s : 0;
    return lo;
}

// ---------------------------------------------------------------------------
// 4-edge-per-lane segmented reduction (proven R2/R5/R6). Equal keys contiguous
// in lane order; key<0 skipped. base may be LDS (atomicAdd -> ds_add).
// ---------------------------------------------------------------------------
template<int NV>
__device__ __forceinline__ void seg_reduce4(const int k[4], float v[4][NV], float* base) {
    const int lane = threadIdx.x & (WAVE - 1);
    const int k0 = k[0], k3 = k[3];
    const bool split = (k0 != k3);
    const int firstLen  = (k[1]==k0) ? ((k[2]==k0) ? ((k[3]==k0)?4:3) : 2) : 1;
    const int lastStart = (k[2]==k3) ? ((k[1]==k3) ? ((k[0]==k3)?0:1) : 2) : 3;

    float vin[NV], vfirst[NV];
#pragma unroll
    for (int c = 0; c < NV; ++c) {
        float s = v[3][c];
        if (lastStart <= 2) s += v[2][c];
        if (lastStart <= 1) s += v[1][c];
        if (lastStart == 0) s += v[0][c];
        vin[c] = s;
        float f = v[0][c];
        if (firstLen >= 2) f += v[1][c];
        if (firstLen >= 3) f += v[2][c];
        if (firstLen >= 4) f += v[3][c];
        vfirst[c] = f;
    }
#pragma unroll
    for (int idx = 1; idx <= 2; ++idx) {
        if (idx >= firstLen && idx < lastStart && k[idx] >= 0) {
#pragma unroll
            for (int c = 0; c < NV; ++c)
                atomicAdd(base + (size_t)k[idx] * NV + c, v[idx][c]);
        }
    }
    float S[NV];
#pragma unroll
    for (int c = 0; c < NV; ++c) S[c] = vin[c];
    const int klast = k3;
#pragma unroll
    for (int d = 1; d < WAVE; d <<= 1) {
        int okey = __shfl_up(klast, d, WAVE);
        float ov[NV];
#pragma unroll
        for (int c = 0; c < NV; ++c) ov[c] = __shfl_up(S[c], d, WAVE);
        if (lane >= d && okey == klast) {
#pragma unroll
            for (int c = 0; c < NV; ++c) S[c] += ov[c];
        }
    }
    const int prevk = __shfl_up(klast, 1, WAVE);
    float P[NV];
#pragma unroll
    for (int c = 0; c < NV; ++c) P[c] = __shfl_up(S[c], 1, WAVE);
    if (split && k0 >= 0) {
        const bool carry = (lane > 0 && prevk == k0);
#pragma unroll
        for (int c = 0; c < NV; ++c)
            atomicAdd(base + (size_t)k0 * NV + c, vfirst[c] + (carry ? P[c] : 0.f));
    }
    const int nk0 = __shfl_down(k0, 1, WAVE);
    const bool tail = (lane == WAVE - 1) || (nk0 != klast);
    if (tail && klast >= 0) {
#pragma unroll
        for (int c = 0; c < NV; ++c)
            atomicAdd(base + (size_t)klast * NV + c, S[c]);
    }
}

struct EW { int jv[4]; float qv[4], dxv[4], dyv[4]; bool okv[4]; };

__device__ __forceinline__ void load_win(long e0, int beg, int end, int E,
        const int* __restrict__ ej, const float* __restrict__ qarr,
        const float2* __restrict__ dirs, EW& w) {
    if (e0 + 3 < (long)E) {
        int4   j4 = *(const int4*)(ej + e0);
        float4 q4 = *(const float4*)(qarr + e0);
        float4 dA = *(const float4*)((const float*)dirs + 2 * e0);
        float4 dB = *(const float4*)((const float*)dirs + 2 * e0 + 4);
        w.jv[0]=j4.x; w.jv[1]=j4.y; w.jv[2]=j4.z; w.jv[3]=j4.w;
        w.qv[0]=q4.x; w.qv[1]=q4.y; w.qv[2]=q4.z; w.qv[3]=q4.w;
        w.dxv[0]=dA.x; w.dyv[0]=dA.y; w.dxv[1]=dA.z; w.dyv[1]=dA.w;
        w.dxv[2]=dB.x; w.dyv[2]=dB.y; w.dxv[3]=dB.z; w.dyv[3]=dB.w;
    } else {
#pragma unroll
        for (int u = 0; u < 4; ++u) {
            long e = e0 + u;
            if (e < (long)E) {
                w.jv[u] = ej[e]; w.qv[u] = qarr[e];
                float2 d = dirs[e]; w.dxv[u] = d.x; w.dyv[u] = d.y;
            } else { w.jv[u]=0; w.qv[u]=0.f; w.dxv[u]=0.f; w.dyv[u]=0.f; }
        }
    }
#pragma unroll
    for (int u = 0; u < 4; ++u) {
        long e = e0 + u;
        w.okv[u] = (e >= (long)beg) && (e < (long)end);
    }
}

// rowptr[t] = first edge e with i[e] >= t (i sorted); also pack vd=(vol,dens).
__global__ void k_prep(const int* __restrict__ ei, const float* __restrict__ vol,
                       const float* __restrict__ dens, int* __restrict__ rowptr,
                       float2* __restrict__ vd, int N, int E) {
    int e = blockIdx.x * blockDim.x + threadIdx.x;
    if (e <= E) {
        int prev = (e == 0) ? -1 : ei[e - 1];
        int cur  = (e == E) ? N  : ei[e];
        for (int t = prev + 1; t <= cur; ++t) rowptr[t] = e;
    }
    if (e < N) vd[e] = make_float2(vol[e], dens[e]);
}

// Fused A+B+C+term1/2 of D:
//   phase A: M(3) + A(1) + B(2) via one 6-wide LDS seg-reduce; stream c_e (half2)
//   pinv -> phase C (gradRho from stash) -> outp = A + 0.5*g·B ; write g2, outp.
__global__ __launch_bounds__(BLOCKT, 4)
void k_AC(const int* __restrict__ ej, const float* __restrict__ qarr,
          const float2* __restrict__ dirs, const float2* __restrict__ vd,
          const int* __restrict__ rowptr, __half2* __restrict__ cst,
          float2* __restrict__ g2, float* __restrict__ outp, int N, int E) {
    __shared__ int    rp[NPB + 1];
    __shared__ float  acc6[NPB * 6];     // m00,m01,m11,A,Bx,By
    __shared__ float  Lild[NPB * 3];
    __shared__ float  gld[NPB * 2];
    __shared__ float2 vdl[NPB];
    const int tid = threadIdx.x;
    const int n0  = blockIdx.x * NPB;
    const int nHi = min(n0 + NPB, N);
    if (tid <= NPB) rp[tid] = rowptr[min(n0 + tid, nHi)];
    if (tid < NPB && n0 + tid < N) vdl[tid] = vd[n0 + tid];
    if (tid < NPB * 6) acc6[tid] = 0.f;
    if (tid < NPB * 2) gld[tid] = 0.f;
    __syncthreads();
    const int  beg = rp[0], end = rp[NPB];
    const long beg4 = (long)beg & ~3L;
    const int  waveBase = tid & ~(WAVE - 1);

    int   li_s[4 * SMAX];
    float w_s[4 * SMAX], dx_s[4 * SMAX], dy_s[4 * SMAX], val_s[4 * SMAX];
#pragma unroll
    for (int x = 0; x < 4 * SMAX; ++x) { li_s[x] = -1; w_s[x]=dx_s[x]=dy_s[x]=val_s[x]=0.f; }

    // ---- phase A ----
#pragma unroll
    for (int c = 0; c < SMAX; ++c) {
        long ebw = beg4 + ((long)c * BLOCKT + waveBase) * 4;
        if (ebw < (long)end) {
            long e0 = beg4 + ((long)c * BLOCKT + tid) * 4;
            EW wd; load_win(e0, beg, end, E, ej, qarr, dirs, wd);
            const bool all4 = wd.okv[0] && wd.okv[1] && wd.okv[2] && wd.okv[3];
            float4 cpack;
            int k[4]; float v[4][6];
#pragma unroll
            for (int u = 0; u < 4; ++u) {
                k[u] = -1;
#pragma unroll
                for (int c2 = 0; c2 < 6; ++c2) v[u][c2] = 0.f;
                if (wd.okv[u]) {
                    int li = li_search(rp, (int)(e0 + u));
                    float q = wd.qv[u], dx = wd.dxv[u], dy = wd.dyv[u];
                    float2 vdj = vd[wd.jv[u]];
                    float wq = wendland_dkdq(q);
                    float s = -2.f * vdj.x * q * wq * INV_H2;   // >= 0
                    float w = wq * INV_H3;
                    float gwx = dx * w, gwy = dy * w;
                    float rx = -dx * q * H, ry = -dy * q * H;
                    float rji2 = rx * rx + ry * ry + EPS_REF;
                    float gT = (gwx * rx + gwy * ry) / rji2;
                    float gv = gT * vdj.x;
                    float rho_ba = REST_RHO * (vdj.y - vdl[li].y);
                    k[u] = li;
                    v[u][0] = s * dx * dx; v[u][1] = s * dx * dy; v[u][2] = s * dy * dy;
                    v[u][3] = rho_ba * gv; v[u][4] = rx * gv;    v[u][5] = ry * gv;
                    __half2 cp = __floats2half2_rn(0.5f * rx * gv, 0.5f * ry * gv);
                    if (all4) (&cpack.x)[u] = h2_as_f(cp);
                    else      cst[e0 + u] = cp;
                    li_s[c*4+u] = li; w_s[c*4+u] = w;
                    dx_s[c*4+u] = dx; dy_s[c*4+u] = dy;
                    val_s[c*4+u] = 2.f * rho_ba * vdj.x;
                }
            }
            if (all4) ((float4*)cst)[e0 >> 2] = cpack;
            seg_reduce4<6>(k, v, acc6);
        }
    }
    // overflow (window > SMAX*1024 edges; practically never at avg degree 32)
    for (int c = SMAX; ; ++c) {
        long ebw = beg4 + ((long)c * BLOCKT + waveBase) * 4;
        if (ebw >= (long)end) break;
        long e0 = beg4 + ((long)c * BLOCKT + tid) * 4;
        EW wd; load_win(e0, beg, end, E, ej, qarr, dirs, wd);
        int k[4]; float v[4][6];
#pragma unroll
        for (int u = 0; u < 4; ++u) {
            k[u] = -1;
#pragma unroll
            for (int c2 = 0; c2 < 6; ++c2) v[u][c2] = 0.f;
            if (wd.okv[u]) {
                int li = li_search(rp, (int)(e0 + u));
                float q = wd.qv[u], dx = wd.dxv[u], dy = wd.dyv[u];
                float2 vdj = vd[wd.jv[u]];
                float wq = wendland_dkdq(q);
                float s = -2.f * vdj.x * q * wq * INV_H2;
                float w = wq * INV_H3;
                float gwx = dx * w, gwy = dy * w;
                float rx = -dx * q * H, ry = -dy * q * H;
                float rji2 = rx * rx + ry * ry + EPS_REF;
                float gT = (gwx * rx + gwy * ry) / rji2;
                float gv = gT * vdj.x;
                float rho_ba = REST_RHO * (vdj.y - vdl[li].y);
                k[u] = li;
                v[u][0] = s * dx * dx; v[u][1] = s * dx * dy; v[u][2] = s * dy * dy;
                v[u][3] = rho_ba * gv; v[u][4] = rx * gv;    v[u][5] = ry * gv;
                cst[e0 + u] = __floats2half2_rn(0.5f * rx * gv, 0.5f * ry * gv);
            }
        }
        seg_reduce4<6>(k, v, acc6);
    }
    __syncthreads();

    // ---- pinv (one lane per node), JAX cutoff semantics ----
    if (tid < NPB) {
        float a = acc6[6*tid], b = acc6[6*tid+1], cc = acc6[6*tid+2];
        float half_tr   = 0.5f * (a + cc);
        float half_diff = 0.5f * (a - cc);
        float disc = sqrtf(half_diff * half_diff + b * b);
        float l1 = half_tr + disc, l2 = half_tr - disc;
        float smax = fmaxf(fabsf(l1), fabsf(l2));
        float cutoff = 2.3841858e-6f * smax;   // rcond = 10*max(2,2)*eps_f32
        float i00 = 0.f, i01 = 0.f, i11 = 0.f;
        if (fabsf(l2) > cutoff) {
            float inv = 1.0f / (a * cc - b * b);
            i00 =  cc * inv; i01 = -b * inv; i11 = a * inv;
        } else if (fabsf(l1) > cutoff) {
            float vax = b,       vay = l1 - a;
            float vbx = l1 - cc, vby = b;
            float na = vax*vax + vay*vay, nb = vbx*vbx + vby*vby;
            float vx, vy, n2;
            if (nb >= na) { vx = vbx; vy = vby; n2 = nb; }
            else          { vx = vax; vy = vay; n2 = na; }
            float inv = 1.0f / (l1 * n2);
            i00 = vx*vx*inv; i01 = vx*vy*inv; i11 = vy*vy*inv;
        }
        Lild[3*tid] = i00; Lild[3*tid+1] = i01; Lild[3*tid+2] = i11;
    }
    __syncthreads();

    // ---- phase C: gradRho from stash ----
#pragma unroll
    for (int c = 0; c < SMAX; ++c) {
        long ebw = beg4 + ((long)c * BLOCKT + waveBase) * 4;
        if (ebw < (long)end) {
            int k[4]; float v[4][2];
#pragma unroll
            for (int u = 0; u < 4; ++u) {
                int li = li_s[c*4+u];
                k[u] = li; v[u][0] = v[u][1] = 0.f;
                if (li >= 0) {
                    float w = w_s[c*4+u], dx = dx_s[c*4+u], dy = dy_s[c*4+u];
                    float gwx = dx * w, gwy = dy * w;
                    float L0 = Lild[3*li], L1 = Lild[3*li+1], L2v = Lild[3*li+2];
                    float gx = L0 * gwx + L1 * gwy;
                    float gy = L1 * gwx + L2v * gwy;
                    float dm = fabsf(gwx) + fabsf(gwy);
                    float nm = fabsf(gx) + fabsf(gy);
                    float change = fabsf(nm - dm) / (dm + 1e-4f * H);
                    if (!(change < 0.1f)) { gx = gwx; gy = gwy; }   // NaN -> fallback
                    v[u][0] = val_s[c*4+u] * gx;
                    v[u][1] = val_s[c*4+u] * gy;
                }
            }
            seg_reduce4<2>(k, v, gld);
        }
    }
    for (int c = SMAX; ; ++c) {   // overflow recompute (rare)
        long ebw = beg4 + ((long)c * BLOCKT + waveBase) * 4;
        if (ebw >= (long)end) break;
        long e0 = beg4 + ((long)c * BLOCKT + tid) * 4;
        EW wd; load_win(e0, beg, end, E, ej, qarr, dirs, wd);
        int k[4]; float v[4][2];
#pragma unroll
        for (int u = 0; u < 4; ++u) {
            k[u] = -1; v[u][0] = v[u][1] = 0.f;
            if (wd.okv[u]) {
                int li = li_search(rp, (int)(e0 + u));
                float q = wd.qv[u], dx = wd.dxv[u], dy = wd.dyv[u];
                float2 vdj = vd[wd.jv[u]];
                float w = wendland_dkdq(q) * INV_H3;
                float gwx = dx * w, gwy = dy * w;
                float L0 = Lild[3*li], L1 = Lild[3*li+1], L2v = Lild[3*li+2];
                float gx = L0 * gwx + L1 * gwy;
                float gy = L1 * gwx + L2v * gwy;
                float dm = fabsf(gwx) + fabsf(gwy);
                float nm = fabsf(gx) + fabsf(gy);
                float change = fabsf(nm - dm) / (dm + 1e-4f * H);
                if (!(change < 0.1f)) { gx = gwx; gy = gwy; }
                float val = 2.f * REST_RHO * (vdj.y - vdl[li].y) * vdj.x;
                k[u] = li; v[u][0] = val * gx; v[u][1] = val * gy;
            }
        }
        seg_reduce4<2>(k, v, gld);
    }
    __syncthreads();
    if (tid < NPB && n0 + tid < N) {
        float gx = gld[2*tid], gy = gld[2*tid+1];
        g2[n0 + tid]   = make_float2(gx, gy);
        outp[n0 + tid] = acc6[6*tid+3] + 0.5f * (gx * acc6[6*tid+4] + gy * acc6[6*tid+5]);
    }
}

// Pass D (term 3 only): out = K_OUT * (outp + sum_e <g[j], c_e>). 66 MB sweep.
__global__ __launch_bounds__(BLOCKT, 4)
void k_D(const int* __restrict__ ej, const __half2* __restrict__ cst,
         const float2* __restrict__ g2, const float* __restrict__ outp,
         const int* __restrict__ rowptr, float* __restrict__ out, int N, int E) {
    __shared__ int   rp[NPB + 1];
    __shared__ float outl[NPB];
    const int tid = threadIdx.x;
    const int n0  = blockIdx.x * NPB;
    const int nHi = min(n0 + NPB, N);
    if (tid <= NPB) rp[tid] = rowptr[min(n0 + tid, nHi)];
    if (tid < NPB) outl[tid] = 0.f;
    __syncthreads();
    const int  beg = rp[0], end = rp[NPB];
    const long beg4 = (long)beg & ~3L;
    const int  waveBase = tid & ~(WAVE - 1);

    for (int c = 0; ; ++c) {
        long ebw = beg4 + ((long)c * BLOCKT + waveBase) * 4;
        if (ebw >= (long)end) break;
        long e0 = beg4 + ((long)c * BLOCKT + tid) * 4;
        int jv[4]; float cv[4]; bool okv[4];
        if (e0 + 3 < (long)E) {
            int4   j4 = *(const int4*)(ej + e0);
            float4 c4 = ((const float4*)cst)[e0 >> 2];
            jv[0]=j4.x; jv[1]=j4.y; jv[2]=j4.z; jv[3]=j4.w;
            cv[0]=c4.x; cv[1]=c4.y; cv[2]=c4.z; cv[3]=c4.w;
        } else {
#pragma unroll
            for (int u = 0; u < 4; ++u) {
                long e = e0 + u;
                if (e < (long)E) { jv[u] = ej[e]; cv[u] = h2_as_f(cst[e]); }
                else             { jv[u] = 0;     cv[u] = 0.f; }
            }
        }
#pragma unroll
        for (int u = 0; u < 4; ++u) {
            long e = e0 + u;
            okv[u] = (e >= (long)beg) && (e < (long)end);
        }
        int k[4]; float v[4][1];
#pragma unroll
        for (int u = 0; u < 4; ++u) {
            k[u] = -1; v[u][0] = 0.f;
            if (okv[u]) {
                int li = li_search(rp, (int)(e0 + u));
                float2 gj = g2[jv[u]];                 // L2-resident gather
                __half2 ch = f_as_h2(cv[u]);
                k[u] = li;
                v[u][0] = gj.x * __low2float(ch) + gj.y * __high2float(ch);
            }
        }
        seg_reduce4<1>(k, v, outl);
    }
    __syncthreads();
    if (tid < NPB && n0 + tid < N)
        out[n0 + tid] = K_OUT * (outp[n0 + tid] + outl[tid]);
}

extern "C" void kernel_launch(void* const* d_in, const int* in_sizes, int n_in,
                              void* d_out, int out_size, void* d_ws, size_t ws_size,
                              hipStream_t stream) {
    const float*  vol  = (const float*)d_in[1];
    const float*  dens = (const float*)d_in[2];
    const float2* dirs = (const float2*)d_in[3];
    const float*  qarr = (const float*)d_in[4];
    const int*    ei   = (const int*)d_in[5];
    const int*    ej   = (const int*)d_in[6];
    const int N = in_sizes[1];
    const int E = in_sizes[4];

    // ws: rowptr int[N+1] | vd f2[N] | g2 f2[N] | outp f[N] | cst h2[E]  (~30.5 MB)
    size_t off = 0;
    auto alloc = [&](size_t bytes) { void* r = (char*)d_ws + off;
                                     off = (off + bytes + 15) & ~(size_t)15; return r; };
    int*     rowptr = (int*)    alloc((size_t)(N + 1) * 4);
    float2*  vd     = (float2*) alloc((size_t)N * 8);
    float2*  g2     = (float2*) alloc((size_t)N * 8);
    float*   outp   = (float*)  alloc((size_t)N * 4);
    __half2* cst    = (__half2*)alloc((size_t)E * 4);
    float*   out    = (float*)d_out;

    const int tb = 256;
    const int gP = (E + 1 + tb - 1) / tb;
    const int gB = (N + NPB - 1) / NPB;

    k_prep<<<gP, tb, 0, stream>>>(ei, vol, dens, rowptr, vd, N, E);
    k_AC  <<<gB, BLOCKT, 0, stream>>>(ej, qarr, dirs, vd, rowptr, cst, g2, outp, N, E);
    k_D   <<<gB, BLOCKT, 0, stream>>>(ej, cst, g2, outp, rowptr, out, N, E);
}